// Round 7
// baseline (395.724 us; speedup 1.0000x reference)
//
#include <hip/hip_runtime.h>
#include <hip/hip_bf16.h>
#include <cstdio>

typedef __bf16  bf16x8 __attribute__((ext_vector_type(8)));
typedef float   f32x4  __attribute__((ext_vector_type(4)));
typedef unsigned short u16;
typedef u16     u16x8  __attribute__((ext_vector_type(8)));
typedef u16     u16x4  __attribute__((ext_vector_type(4)));

// ---------- helpers ----------

__device__ __forceinline__ void gld_lds16(const void* g, void* l) {
  // async global->LDS, 16B per lane; LDS dest is wave-uniform base + lane*16
  __builtin_amdgcn_global_load_lds(
      (const __attribute__((address_space(1))) unsigned int*)g,
      (__attribute__((address_space(3))) unsigned int*)l,
      16, 0, 0);
}

__device__ __forceinline__ u16 f2bf(float f) {
  union { float f; unsigned int u; } c{f};
  unsigned int u = c.u;
  u += 0x7fffu + ((u >> 16) & 1u);   // round-to-nearest-even
  return (u16)(u >> 16);
}

__device__ __forceinline__ float bf2f(u16 h) {
  union { unsigned int u; float f; } c{(unsigned int)h << 16};
  return c.f;
}

enum { EPI_QKV = 0, EPI_QK = 1, EPI_PV = 2, EPI_VT = 3 };

// ---------- prep: cast x -> bf16, pack/transpose weights, zero rowsums ----------

__global__ __launch_bounds__(256) void prep_kernel(const float* __restrict__ x,
                                                   u16* __restrict__ xbf,
                                                   const float* __restrict__ w,
                                                   u16* __restrict__ wt,
                                                   float* __restrict__ rs) {
  __shared__ float tile[32][33];
  const int bid = blockIdx.x;
  if (bid < 4096) {
    const int i = (bid * 256 + threadIdx.x) * 8;
    float4 a = *(const float4*)(x + i);
    float4 b = *(const float4*)(x + i + 4);
    u16x8 r;
    r[0] = f2bf(a.x); r[1] = f2bf(a.y); r[2] = f2bf(a.z); r[3] = f2bf(a.w);
    r[4] = f2bf(b.x); r[5] = f2bf(b.y); r[6] = f2bf(b.z); r[7] = f2bf(b.w);
    *(u16x8*)(xbf + i) = r;
  } else if (bid < 7168) {
    // WT[s][e][d] = w[s][d][e], s in 0..2
    const int b2 = bid - 4096;
    const int s = b2 >> 10, r = b2 & 1023;
    const int e0 = (r & 31) * 32, d0 = (r >> 5) * 32;
    const int tx = threadIdx.x & 31, ty = threadIdx.x >> 5;
    const float* in = w + (size_t)s * 1048576;
#pragma unroll
    for (int j = 0; j < 4; ++j)
      tile[ty + j * 8][tx] = in[(size_t)(d0 + ty + j * 8) * 1024 + e0 + tx];
    __syncthreads();
    u16* o = wt + (size_t)s * 1048576;
#pragma unroll
    for (int j = 0; j < 4; ++j)
      o[(size_t)(e0 + ty + j * 8) * 1024 + d0 + tx] = f2bf(tile[tx][ty + j * 8]);
  } else {
    const float4 z = {0.f, 0.f, 0.f, 0.f};
#pragma unroll
    for (int j = 0; j < 8; ++j)
      ((float4*)rs)[threadIdx.x + j * 256] = z;  // 8192 floats
  }
}

// ---------- XCD-aware bijective block swizzle (T1) ----------

template <int GX, int GY, int GZ>
__device__ __forceinline__ void xcd_swz(int& bx, int& by, int& bz) {
  constexpr int NWG = GX * GY * GZ;
  static_assert(NWG % 8 == 0, "grid must be divisible by 8");
  constexpr int Q8 = NWG / 8;
  int flat = blockIdx.x + GX * (blockIdx.y + GY * blockIdx.z);
  flat = (flat & 7) * Q8 + (flat >> 3);
  bx = flat % GX;
  by = (flat / GX) % GY;
  bz = flat / (GX * GY);
}

// ================= 256x256 BT-GEMM, 2-cluster pipelined schedule =================
// C[M,N] = A[M,K]*B[N,K]^T. 512 thr = 8 waves (2M x 4N), per-wave 128x64,
// BK=64, LDS 128 KiB (buf0: A@0 B@16384, buf1: A@32768 B@49152, u16 units).
// XOR-swizzle unchanged: 16B chunk c of row r at slot c ^ (r&7).
//
// Key idea (m201 mechanism, finally decoded): every ds_read is issued one
// 32-MFMA cluster BEFORE its consumption, and lgkmcnt(0) drains come AFTER
// a cluster (returns hidden under MFMA). 2 barriers + 1 counted vmcnt/tile.
//
// Per tile t (cur = t data landed, nxt = t+1 staged/in-flight, 8 vmem out):
//  Ph1: stage (t+2)B->cur.B; issue a1_t reads; MFMA C1 = a0_t x {b0,b1}_t
//       (operands read during t-1's Ph2, already drained);
//       lgkmcnt(0) [a1 drained, hid under C1]; vmcnt(4) [t+1 fully landed];
//       barrier.
//  Ph2: stage (t+2)A->cur.A; issue reads a0,b of (t+1) from nxt (legal:
//       vmcnt'd+barrier'd); MFMA C2 = a1_t x {b1,b0}_t;
//       lgkmcnt(0) [t+1 frags drained, hid under C2]; barrier; swap.
// Restage safety: region restaged only after a barrier all waves reached
// having lgkm-drained their reads of it (cur.B: prev-Ph2 lgkm; cur.A: Ph1
// lgkm). b-frags span both clusters -> register double-buffer across the
// 2x-unrolled tile parity (all indexing compile-time).
// Ledger: start 8 out = (t+1){B,A}. Ph1 +4 -> vmcnt(4) leaves (t+2)B.
// Ph2 +4 -> 8 = (t+2){B,A}. Tails: stages skipped at t+2>=nt (vmcnt(0)),
// reads skipped at t+1>=nt.

__device__ __forceinline__ void stage_half(const u16* __restrict__ g, int ld, int k0,
                                           u16* ldsb, int w, int l) {
  const int srow = l >> 3;                          // row within 8-row chunk
  const int scol = ((l & 7) ^ (srow & 7)) * 8;      // swizzled 16B chunk (u16 units)
#pragma unroll
  for (int q = 0; q < 2; ++q) {
    const int r = w * 16 + q * 8;                   // 8 waves x 2 x 8 rows = 128
    gld_lds16(g + (long)(r + srow) * ld + k0 + scol, (void*)(ldsb + r * 64));
  }
}

#define KT2(CA, CB, NA, NB, BC0, BC1, BN0, BN1, TT)                               \
  do {                                                                            \
    /* ---- Ph1: stage (t+2)B -> cur.B; read a1_t; MFMA C1 (a0 x b) ---- */       \
    if ((TT) + 2 < nt) {                                                          \
      stage_half(Br,             ldb, ((TT) + 2) << 6, lds + (CB),        w, l);  \
      stage_half(Br + 128 * ldb, ldb, ((TT) + 2) << 6, lds + (CB) + 8192, w, l);  \
    }                                                                             \
    _Pragma("unroll")                                                             \
    for (int mi = 0; mi < 4; ++mi)                                                \
      _Pragma("unroll")                                                           \
      for (int j = 0; j < 2; ++j)                                                 \
        a1[mi][j] = *(const bf16x8*)(lds + (CA) +                                 \
            (wm * 128 + (mi + 4) * 16 + lr) * 64 + (((j * 4 + lq) ^ rsw) * 8));   \
    __builtin_amdgcn_s_setprio(1);                                                \
    _Pragma("unroll")                                                             \
    for (int mi = 0; mi < 4; ++mi)                                                \
      _Pragma("unroll")                                                           \
      for (int ni = 0; ni < 2; ++ni)                                              \
        _Pragma("unroll")                                                         \
        for (int j = 0; j < 2; ++j) {                                             \
          acc[mi][ni]     = __builtin_amdgcn_mfma_f32_16x16x32_bf16(              \
              a0[mi][j], BC0[ni][j], acc[mi][ni], 0, 0, 0);                       \
          acc[mi][ni + 2] = __builtin_amdgcn_mfma_f32_16x16x32_bf16(              \
              a0[mi][j], BC1[ni][j], acc[mi][ni + 2], 0, 0, 0);                   \
        }                                                                         \
    __builtin_amdgcn_s_setprio(0);                                                \
    asm volatile("s_waitcnt lgkmcnt(0)" ::: "memory");                            \
    if ((TT) + 2 < nt) asm volatile("s_waitcnt vmcnt(4)" ::: "memory");           \
    else               asm volatile("s_waitcnt vmcnt(0)" ::: "memory");           \
    __builtin_amdgcn_s_barrier();                                                 \
    /* ---- Ph2: stage (t+2)A -> cur.A; read (t+1){a0,b}; MFMA C2 (a1 x b) */     \
    if ((TT) + 2 < nt) {                                                          \
      stage_half(Ar,             lda, ((TT) + 2) << 6, lds + (CA),        w, l);  \
      stage_half(Ar + 128 * lda, lda, ((TT) + 2) << 6, lds + (CA) + 8192, w, l);  \
    }                                                                             \
    if ((TT) + 1 < nt) {                                                          \
      _Pragma("unroll")                                                           \
      for (int mi = 0; mi < 4; ++mi)                                              \
        _Pragma("unroll")                                                         \
        for (int j = 0; j < 2; ++j)                                               \
          a0[mi][j] = *(const bf16x8*)(lds + (NA) +                               \
              (wm * 128 + mi * 16 + lr) * 64 + (((j * 4 + lq) ^ rsw) * 8));       \
      _Pragma("unroll")                                                           \
      for (int ni = 0; ni < 2; ++ni)                                              \
        _Pragma("unroll")                                                         \
        for (int j = 0; j < 2; ++j) {                                             \
          BN0[ni][j] = *(const bf16x8*)(lds + (NB) +                              \
              (wn * 64 + ni * 16 + lr) * 64 + (((j * 4 + lq) ^ rsw) * 8));        \
          BN1[ni][j] = *(const bf16x8*)(lds + (NB) +                              \
              (wn * 64 + (ni + 2) * 16 + lr) * 64 + (((j * 4 + lq) ^ rsw) * 8));  \
        }                                                                         \
    }                                                                             \
    __builtin_amdgcn_s_setprio(1);                                                \
    _Pragma("unroll")                                                             \
    for (int mi = 0; mi < 4; ++mi)                                                \
      _Pragma("unroll")                                                           \
      for (int ni = 0; ni < 2; ++ni)                                              \
        _Pragma("unroll")                                                         \
        for (int j = 0; j < 2; ++j) {                                             \
          acc[mi + 4][ni + 2] = __builtin_amdgcn_mfma_f32_16x16x32_bf16(          \
              a1[mi][j], BC1[ni][j], acc[mi + 4][ni + 2], 0, 0, 0);               \
          acc[mi + 4][ni]     = __builtin_amdgcn_mfma_f32_16x16x32_bf16(          \
              a1[mi][j], BC0[ni][j], acc[mi + 4][ni], 0, 0, 0);                   \
        }                                                                         \
    __builtin_amdgcn_s_setprio(0);                                                \
    asm volatile("s_waitcnt lgkmcnt(0)" ::: "memory");                            \
    __builtin_amdgcn_s_barrier();                                                 \
  } while (0)

template <int EPI, int GX, int GY, int GZ>
__global__ __launch_bounds__(512, 2)
void gemm256_bt(const u16* __restrict__ A, const u16* __restrict__ B,
                void* __restrict__ Cv, int K, int lda, int ldb, int ldc,
                long sA, long sB, long sC,
                float* __restrict__ rowsum, u16* __restrict__ auxK, u16* __restrict__ auxV) {
  __shared__ __align__(16) u16 lds[65536];          // 128 KiB

  const int t = threadIdx.x;
  const int w = t >> 6, l = t & 63;
  const int wm = w >> 2, wn = w & 3;
  const int lr = l & 15, lq = l >> 4;
  const int rsw = l & 7;                            // read-side swizzle key
  int bxs, bys, bz;
  xcd_swz<GX, GY, GZ>(bxs, bys, bz);
  const int m0 = bys * 256, n0 = bxs * 256;
  const u16* Ar = A + (long)bz * sA + (long)m0 * lda;
  const u16* Br = B + (long)bz * sB + (long)n0 * ldb;

  const int nt = K >> 6;                            // REQUIRES nt even

  f32x4 acc[8][4] = {};
  bf16x8 a0[4][2], a1[4][2];
  bf16x8 bE0[2][2], bE1[2][2], bO0[2][2], bO1[2][2];

  // ---- prologue: stage t0 {B,A} -> buf0; t1 {B,A} -> buf1 ----
  stage_half(Br,             ldb, 0, lds + 16384, w, l);
  stage_half(Br + 128 * ldb, ldb, 0, lds + 24576, w, l);
  stage_half(Ar,             lda, 0, lds,         w, l);
  stage_half(Ar + 128 * lda, lda, 0, lds + 8192,  w, l);
  if (nt > 1) {
    stage_half(Br,             ldb, 64, lds + 49152, w, l);
    stage_half(Br + 128 * ldb, ldb, 64, lds + 57344, w, l);
    stage_half(Ar,             lda, 64, lds + 32768, w, l);
    stage_half(Ar + 128 * lda, lda, 64, lds + 40960, w, l);
    asm volatile("s_waitcnt vmcnt(8)" ::: "memory");   // t0 fully landed
  } else {
    asm volatile("s_waitcnt vmcnt(0)" ::: "memory");
  }
  __builtin_amdgcn_s_barrier();

  // ---- prime: read tile0's a0 + b (even-parity regs) ----
#pragma unroll
  for (int mi = 0; mi < 4; ++mi)
#pragma unroll
    for (int j = 0; j < 2; ++j)
      a0[mi][j] = *(const bf16x8*)(lds + (wm * 128 + mi * 16 + lr) * 64 +
                                   (((j * 4 + lq) ^ rsw) * 8));
#pragma unroll
  for (int ni = 0; ni < 2; ++ni)
#pragma unroll
    for (int j = 0; j < 2; ++j) {
      bE0[ni][j] = *(const bf16x8*)(lds + 16384 + (wn * 64 + ni * 16 + lr) * 64 +
                                    (((j * 4 + lq) ^ rsw) * 8));
      bE1[ni][j] = *(const bf16x8*)(lds + 16384 + (wn * 64 + (ni + 2) * 16 + lr) * 64 +
                                    (((j * 4 + lq) ^ rsw) * 8));
    }
  asm volatile("s_waitcnt lgkmcnt(0)" ::: "memory");
  __builtin_amdgcn_s_barrier();   // all waves' prime-reads done before t0-Ph1 stage

  for (int tt = 0; tt < nt; tt += 2) {
    KT2(0,     16384, 32768, 49152, bE0, bE1, bO0, bO1, tt);      // even: cur=buf0
    KT2(32768, 49152, 0,     16384, bO0, bO1, bE0, bE1, tt + 1);  // odd:  cur=buf1
  }

  // ======================= epilogues =======================
  if (EPI == EPI_QK) {
#pragma unroll
    for (int mi = 0; mi < 8; ++mi) {
#pragma unroll
      for (int i = 0; i < 4; ++i) {
        const int row = m0 + wm * 128 + mi * 16 + lq * 4 + i;
        float rs = 0.f;
#pragma unroll
        for (int ni = 0; ni < 4; ++ni) {
          const int col = n0 + wn * 64 + ni * 16 + lr;
          const u16 h = f2bf(__expf(acc[mi][ni][i] * 0.03125f));  // unnorm prob
          ((u16*)Cv)[(long)bz * sC + (long)row * ldc + col] = h;
          rs += bf2f(h);
        }
        rs += __shfl_xor(rs, 1, 64);
        rs += __shfl_xor(rs, 2, 64);
        rs += __shfl_xor(rs, 4, 64);
        rs += __shfl_xor(rs, 8, 64);
        if (lr == 0) atomicAdd(rowsum + bz * 2048 + row, rs);
      }
    }
    return;
  }

  // EPI_QKV dense (Q or K slice; n0 < 2048 always with the split launch)
  u16* qkv_out = (n0 < 1024) ? (u16*)Cv : auxK;
  const int nl0 = n0 & 1023;
#pragma unroll
  for (int mi = 0; mi < 8; ++mi) {
#pragma unroll
    for (int i = 0; i < 4; ++i) {
      const int row = m0 + wm * 128 + mi * 16 + lq * 4 + i;
#pragma unroll
      for (int ni = 0; ni < 4; ++ni)
        qkv_out[(long)row * 1024 + nl0 + wn * 64 + ni * 16 + lr] = f2bf(acc[mi][ni][i]);
    }
  }
}

// ---------- legacy 128x128 BT-GEMM (PV; V-projection-as-VT) ----------

template <int EPI, int GX, int GY, int GZ>
__global__ __launch_bounds__(256)
void gemm_bt(const u16* __restrict__ A, const u16* __restrict__ B,
             void* __restrict__ Cv, int K, int lda, int ldb, int ldc,
             long sA, long sB, long sC,
             float* __restrict__ rowsum, u16* __restrict__ auxK, u16* __restrict__ auxV) {
  __shared__ __align__(16) u16 lds[128 * 128];
  u16* As = lds;
  u16* Bs = lds + 128 * 64;

  const int t = threadIdx.x;
  const int w = t >> 6, l = t & 63;
  int bxs, bys, bz;
  xcd_swz<GX, GY, GZ>(bxs, bys, bz);
  const u16* Ab = A + (long)bz * sA;
  const u16* Bb = B + (long)bz * sB;
  const int m0 = bys * 128, n0 = bxs * 128;
  const int wm = w & 1, wn = w >> 1;
  const int lr = l & 15, lq = l >> 4;
  const int srow = l >> 3;
  const int scol = ((l & 7) ^ ((l >> 3) & 7)) * 8;
  const int rsw = l & 7;

  f32x4 acc[4][4] = {};

  for (int k0 = 0; k0 < K; k0 += 64) {
    __syncthreads();
#pragma unroll
    for (int c = 0; c < 4; ++c) {
      const int rb = (w * 4 + c) * 8;
      gld_lds16(Ab + (long)(m0 + rb + srow) * lda + k0 + scol, (void*)(As + rb * 64));
      gld_lds16(Bb + (long)(n0 + rb + srow) * ldb + k0 + scol, (void*)(Bs + rb * 64));
    }
    __syncthreads();
#pragma unroll
    for (int j = 0; j < 2; ++j) {
      bf16x8 af[4], bfr[4];
#pragma unroll
      for (int i = 0; i < 4; ++i) {
        const int ch = ((j * 4 + lq) ^ rsw) * 8;
        af[i]  = *(const bf16x8*)(As + (wm * 64 + i * 16 + lr) * 64 + ch);
        bfr[i] = *(const bf16x8*)(Bs + (wn * 64 + i * 16 + lr) * 64 + ch);
      }
#pragma unroll
      for (int mi = 0; mi < 4; ++mi)
#pragma unroll
        for (int ni = 0; ni < 4; ++ni)
          acc[mi][ni] = __builtin_amdgcn_mfma_f32_16x16x32_bf16(af[mi], bfr[ni], acc[mi][ni], 0, 0, 0);
    }
  }

#pragma unroll
  for (int mi = 0; mi < 4; ++mi) {
#pragma unroll
    for (int i = 0; i < 4; ++i) {
      const int row = m0 + wm * 64 + mi * 16 + lq * 4 + i;
      float inv;
      if (EPI == EPI_PV) inv = 1.0f / rowsum[bz * 2048 + row];
      float rs = 0.f;
#pragma unroll
      for (int ni = 0; ni < 4; ++ni) {
        const float val = acc[mi][ni][i];
        const int col = n0 + wn * 64 + ni * 16 + lr;
        if (EPI == EPI_VT) {
          // row = e in [0,1024), col = global k in [0,8192); batch = col>>11
          auxV[(long)(col >> 11) * 2097152 + (long)row * 2048 + (col & 2047)] = f2bf(val);
        } else if (EPI == EPI_QK) {
          const u16 h = f2bf(__expf(val * 0.03125f));
          ((u16*)Cv)[(long)bz * sC + (long)row * ldc + col] = h;
          rs += bf2f(h);
        } else {  // EPI_PV
          ((float*)Cv)[(long)bz * sC + (long)row * ldc + col] = val * inv;
        }
      }
      if (EPI == EPI_QK) {
        rs += __shfl_xor(rs, 1, 64);
        rs += __shfl_xor(rs, 2, 64);
        rs += __shfl_xor(rs, 4, 64);
        rs += __shfl_xor(rs, 8, 64);
        if (lr == 0) atomicAdd(rowsum + bz * 2048 + row, rs);
      }
    }
  }
}

// ---------- launch ----------

extern "C" void kernel_launch(void* const* d_in, const int* in_sizes, int n_in,
                              void* d_out, int out_size, void* d_ws, size_t ws_size,
                              hipStream_t stream) {
  (void)in_sizes; (void)n_in; (void)out_size;
  const float* x    = (const float*)d_in[0];
  const float* kern = (const float*)d_in[1];
  float* out = (float*)d_out;
  char* ws = (char*)d_ws;
  const size_t MB = 1024 * 1024;
  u16*   xbf  = (u16*)(ws);              // 16 MB: [8192][1024] bf16
  u16*   WT   = (u16*)(ws + 16 * MB);    //  6 MB: [3][1024][1024] bf16
  u16*   Qc   = (u16*)(ws + 22 * MB);    // 16 MB: [8192][1024] bf16
  u16*   Kc   = (u16*)(ws + 38 * MB);    // 16 MB: [8192][1024] bf16
  u16*   VT   = (u16*)(ws + 54 * MB);    // 16 MB: [4][1024e][2048k] bf16
  u16*   SP   = (u16*)(ws + 70 * MB);    // 32 MB: [4][2048][2048] bf16 unnormalized probs
  float* RS   = (float*)(ws + 102 * MB); // 32 KB: [4][2048] fp32 row sums
  if (ws_size < 102 * MB + 32768)
    fprintf(stderr, "WARNING: ws_size %zu too small\n", ws_size);

  prep_kernel<<<7169, 256, 0, stream>>>(x, xbf, kern, WT, RS);
  // Q|K projection: M=8192, N=2048 (Q|K), K=1024 -> 8x32 = 256 blocks = 1/CU
  gemm256_bt<EPI_QKV, 8, 32, 1><<<dim3(8, 32, 1), 512, 0, stream>>>(
      xbf, WT, Qc, 1024, 1024, 1024, 1024, 0, 0, 0, nullptr, Kc, nullptr);
  // V projection, transposed form: VT[e][k] = sum_d WvT[e][d]*x[k][d]
  // M=1024(e), N=8192(k) -> 64x8 = 512 blocks = 2/CU, tail-free
  gemm_bt<EPI_VT, 64, 8, 1><<<dim3(64, 8, 1), 256, 0, stream>>>(
      WT + 2 * 1048576, xbf, nullptr, 1024, 1024, 1024, 2048,
      0, 0, 0, nullptr, nullptr, VT);
  // P'[b][q][k] = exp((Q[b][q,:].K[b][k,:])/32), rowsum accumulated; 256 blocks = 1/CU
  gemm256_bt<EPI_QK, 8, 8, 4><<<dim3(8, 8, 4), 512, 0, stream>>>(
      Qc, Kc, SP, 1024, 1024, 1024, 2048,
      2048L * 1024, 2048L * 1024, 2048L * 2048, RS, nullptr, nullptr);
  // out[b][q][e] = (P'[b][q,:] . VT[b][e,:]) / rowsum[b][q]
  gemm_bt<EPI_PV, 8, 16, 4><<<dim3(8, 16, 4), 256, 0, stream>>>(
      SP, VT, out, 2048, 2048, 2048, 1024,
      2048L * 2048, 1024L * 2048, 2048L * 1024, RS, nullptr, nullptr);
}

// Round 8
// 234.000 us; speedup vs baseline: 1.6911x; 1.6911x over previous
//
#include <hip/hip_runtime.h>
#include <hip/hip_bf16.h>
#include <cstdio>

typedef __bf16  bf16x8 __attribute__((ext_vector_type(8)));
typedef float   f32x4  __attribute__((ext_vector_type(4)));
typedef unsigned short u16;
typedef u16     u16x8  __attribute__((ext_vector_type(8)));
typedef u16     u16x4  __attribute__((ext_vector_type(4)));

// ---------- helpers ----------

__device__ __forceinline__ void gld_lds16(const void* g, void* l) {
  // async global->LDS, 16B per lane; LDS dest is wave-uniform base + lane*16
  __builtin_amdgcn_global_load_lds(
      (const __attribute__((address_space(1))) unsigned int*)g,
      (__attribute__((address_space(3))) unsigned int*)l,
      16, 0, 0);
}

__device__ __forceinline__ u16 f2bf(float f) {
  union { float f; unsigned int u; } c{f};
  unsigned int u = c.u;
  u += 0x7fffu + ((u >> 16) & 1u);   // round-to-nearest-even
  return (u16)(u >> 16);
}

__device__ __forceinline__ float bf2f(u16 h) {
  union { unsigned int u; float f; } c{(unsigned int)h << 16};
  return c.f;
}

enum { EPI_QKV = 0, EPI_QK = 1, EPI_PV = 2 };

// ---------- prep: cast x -> bf16, pack/transpose weights ----------
// grid: [0,4096) cast blocks, [4096,7168) weight tiles

__global__ __launch_bounds__(256) void prep_kernel(const float* __restrict__ x,
                                                   u16* __restrict__ xbf,
                                                   const float* __restrict__ w,
                                                   u16* __restrict__ wt) {
  __shared__ float tile[32][33];
  const int bid = blockIdx.x;
  if (bid < 4096) {
    const int i = (bid * 256 + threadIdx.x) * 8;
    float4 a = *(const float4*)(x + i);
    float4 b = *(const float4*)(x + i + 4);
    u16x8 r;
    r[0] = f2bf(a.x); r[1] = f2bf(a.y); r[2] = f2bf(a.z); r[3] = f2bf(a.w);
    r[4] = f2bf(b.x); r[5] = f2bf(b.y); r[6] = f2bf(b.z); r[7] = f2bf(b.w);
    *(u16x8*)(xbf + i) = r;
  } else {
    // WT[s][e][d] = w[s][d][e], s in 0..2
    const int b2 = bid - 4096;
    const int s = b2 >> 10, r = b2 & 1023;
    const int e0 = (r & 31) * 32, d0 = (r >> 5) * 32;
    const int tx = threadIdx.x & 31, ty = threadIdx.x >> 5;
    const float* in = w + (size_t)s * 1048576;
#pragma unroll
    for (int j = 0; j < 4; ++j)
      tile[ty + j * 8][tx] = in[(size_t)(d0 + ty + j * 8) * 1024 + e0 + tx];
    __syncthreads();
    u16* o = wt + (size_t)s * 1048576;
#pragma unroll
    for (int j = 0; j < 4; ++j)
      o[(size_t)(e0 + ty + j * 8) * 1024 + d0 + tx] = f2bf(tile[tx][ty + j * 8]);
  }
}

// ---------- XCD-aware bijective block swizzle (T1) ----------
// Dispatch order is x-fastest; block d lands on XCD d%8. Remap so each XCD
// owns a CONTIGUOUS run of logical tiles (consecutive x share the A-panel ->
// panel stays in that XCD's L2). Requires NWG % 8 == 0 (all our grids).

template <int GX, int GY, int GZ>
__device__ __forceinline__ void xcd_swz(int& bx, int& by, int& bz) {
  constexpr int NWG = GX * GY * GZ;
  static_assert(NWG % 8 == 0, "grid must be divisible by 8");
  constexpr int Q8 = NWG / 8;
  int flat = blockIdx.x + GX * (blockIdx.y + GY * blockIdx.z);
  flat = (flat & 7) * Q8 + (flat >> 3);
  bx = flat % GX;
  by = (flat / GX) % GY;
  bz = flat / (GX * GY);
}

// ================= 256x256 8-phase BT-GEMM (round-4 schedule, best) ==========
// C[M,N] = A[M,K] * B[N,K]^T, bf16 in, fp32 acc.
// 512 threads = 8 waves (2M x 4N); per-wave 128x64 out; BK=64; LDS 128 KiB.
// XOR-swizzle: 16B chunk c of row r lives at slot c ^ (r&7).
// Stage ledger (verified r2/r4): P1 stages (t+1)A1->nxt.A1; P2 none;
// P3 (t+2)B0->cur.B0; P4 (t+2)B1->cur.B1 + (t+2)A0->cur.A0; vmcnt(6) at P4.

__device__ __forceinline__ void stage_half(const u16* __restrict__ g, int ld, int k0,
                                           u16* ldsb, int w, int l) {
  const int srow = l >> 3;                          // row within 8-row chunk
  const int scol = ((l & 7) ^ (srow & 7)) * 8;      // swizzled 16B chunk (u16 units)
#pragma unroll
  for (int q = 0; q < 2; ++q) {
    const int r = w * 16 + q * 8;                   // 8 waves x 2 x 8 rows = 128
    gld_lds16(g + (long)(r + srow) * ld + k0 + scol, (void*)(ldsb + r * 64));
  }
}

template <int EPI, int GX, int GY, int GZ>
__global__ __launch_bounds__(512, 2)
void gemm256_bt(const u16* __restrict__ A, const u16* __restrict__ B,
                void* __restrict__ Cv, int K, int lda, int ldb, int ldc,
                long sA, long sB, long sC,
                u16* __restrict__ auxK, u16* __restrict__ auxV) {
  __shared__ __align__(16) u16 lds[65536];          // 128 KiB

  const int t = threadIdx.x;
  const int w = t >> 6, l = t & 63;
  const int wm = w >> 2, wn = w & 3;
  const int lr = l & 15, lq = l >> 4;
  const int rsw = l & 7;                            // read-side swizzle key
  int bxs, bys, bz;
  xcd_swz<GX, GY, GZ>(bxs, bys, bz);
  const int m0 = bys * 256, n0 = bxs * 256;
  const u16* Ar = A + (long)bz * sA + (long)m0 * lda;
  const u16* Br = B + (long)bz * sB + (long)n0 * ldb;

  u16* curA = lds;
  u16* curB = lds + 16384;
  u16* nxtA = lds + 32768;
  u16* nxtB = lds + 49152;

  const int nt = K >> 6;

  f32x4 acc[8][4] = {};

  // ---- prologue: tile0 {A0,B0,B1,A1} -> cur; tile1 {A0,B0,B1} -> nxt ----
  stage_half(Ar,             lda, 0, curA,        w, l);
  stage_half(Br,             ldb, 0, curB,        w, l);
  stage_half(Br + 128 * ldb, ldb, 0, curB + 8192, w, l);
  stage_half(Ar + 128 * lda, lda, 0, curA + 8192, w, l);
  asm volatile("s_waitcnt vmcnt(4)" ::: "memory");
  if (nt > 1) {
    stage_half(Ar,             lda, 64, nxtA,        w, l);
    stage_half(Br,             ldb, 64, nxtB,        w, l);
    stage_half(Br + 128 * ldb, ldb, 64, nxtB + 8192, w, l);
    asm volatile("s_waitcnt vmcnt(6)" ::: "memory");   // tile0 fully landed
  } else {
    asm volatile("s_waitcnt vmcnt(0)" ::: "memory");
  }
  __builtin_amdgcn_s_barrier();

  for (int tt = 0; tt < nt; ++tt) {
    const int kc = tt << 6;
    bf16x8 a0[4][2], a1[4][2], b0[2][2], b1[2][2];

    // -------- phase 1: read A-half-lo(8) + B-quarter-0(4); stage (t+1)A1 ----
#pragma unroll
    for (int mi = 0; mi < 4; ++mi)
#pragma unroll
      for (int j = 0; j < 2; ++j)
        a0[mi][j] = *(const bf16x8*)(curA + (wm * 128 + mi * 16 + lr) * 64 +
                                     (((j * 4 + lq) ^ rsw) * 8));
#pragma unroll
    for (int ni = 0; ni < 2; ++ni)
#pragma unroll
      for (int j = 0; j < 2; ++j)
        b0[ni][j] = *(const bf16x8*)(curB + (wn * 64 + ni * 16 + lr) * 64 +
                                     (((j * 4 + lq) ^ rsw) * 8));
    if (tt + 1 < nt)
      stage_half(Ar + 128 * lda, lda, kc + 64, nxtA + 8192, w, l);
    __builtin_amdgcn_s_barrier();
    asm volatile("s_waitcnt lgkmcnt(0)" ::: "memory");
    __builtin_amdgcn_sched_barrier(0);
    __builtin_amdgcn_s_setprio(1);
#pragma unroll
    for (int mi = 0; mi < 4; ++mi)
#pragma unroll
      for (int ni = 0; ni < 2; ++ni)
#pragma unroll
        for (int j = 0; j < 2; ++j)
          acc[mi][ni] = __builtin_amdgcn_mfma_f32_16x16x32_bf16(a0[mi][j], b0[ni][j], acc[mi][ni], 0, 0, 0);
    __builtin_amdgcn_s_setprio(0);
    __builtin_amdgcn_s_barrier();

    // -------- phase 2: read B-quarter-1(4); no stage (cur.A live till P3) ---
#pragma unroll
    for (int ni = 0; ni < 2; ++ni)
#pragma unroll
      for (int j = 0; j < 2; ++j)
        b1[ni][j] = *(const bf16x8*)(curB + (wn * 64 + (ni + 2) * 16 + lr) * 64 +
                                     (((j * 4 + lq) ^ rsw) * 8));
    __builtin_amdgcn_s_barrier();
    asm volatile("s_waitcnt lgkmcnt(0)" ::: "memory");
    __builtin_amdgcn_sched_barrier(0);
    __builtin_amdgcn_s_setprio(1);
#pragma unroll
    for (int mi = 0; mi < 4; ++mi)
#pragma unroll
      for (int ni = 0; ni < 2; ++ni)
#pragma unroll
        for (int j = 0; j < 2; ++j)
          acc[mi][ni + 2] = __builtin_amdgcn_mfma_f32_16x16x32_bf16(a0[mi][j], b1[ni][j], acc[mi][ni + 2], 0, 0, 0);
    __builtin_amdgcn_s_setprio(0);
    __builtin_amdgcn_s_barrier();

    // -------- phase 3: read A-half-hi(8); stage (t+2)B0 ---------------------
#pragma unroll
    for (int mi = 0; mi < 4; ++mi)
#pragma unroll
      for (int j = 0; j < 2; ++j)
        a1[mi][j] = *(const bf16x8*)(curA + (wm * 128 + (mi + 4) * 16 + lr) * 64 +
                                     (((j * 4 + lq) ^ rsw) * 8));
    if (tt + 2 < nt)
      stage_half(Br, ldb, kc + 128, curB, w, l);
    __builtin_amdgcn_s_barrier();
    asm volatile("s_waitcnt lgkmcnt(0)" ::: "memory");
    __builtin_amdgcn_sched_barrier(0);
    __builtin_amdgcn_s_setprio(1);
#pragma unroll
    for (int mi = 0; mi < 4; ++mi)
#pragma unroll
      for (int ni = 0; ni < 2; ++ni)
#pragma unroll
        for (int j = 0; j < 2; ++j)
          acc[mi + 4][ni + 2] = __builtin_amdgcn_mfma_f32_16x16x32_bf16(a1[mi][j], b1[ni][j], acc[mi + 4][ni + 2], 0, 0, 0);
    __builtin_amdgcn_s_setprio(0);
    __builtin_amdgcn_s_barrier();

    // -------- phase 4: stage (t+2)B1 + (t+2)A0; MFMA hi,lo; tile-end vmcnt --
    if (tt + 2 < nt) {
      stage_half(Br + 128 * ldb, ldb, kc + 128, curB + 8192, w, l);
      stage_half(Ar,             lda, kc + 128, curA,        w, l);
    }
    __builtin_amdgcn_s_barrier();
    __builtin_amdgcn_sched_barrier(0);
    __builtin_amdgcn_s_setprio(1);
#pragma unroll
    for (int mi = 0; mi < 4; ++mi)
#pragma unroll
      for (int ni = 0; ni < 2; ++ni)
#pragma unroll
        for (int j = 0; j < 2; ++j)
          acc[mi + 4][ni] = __builtin_amdgcn_mfma_f32_16x16x32_bf16(a1[mi][j], b0[ni][j], acc[mi + 4][ni], 0, 0, 0);
    __builtin_amdgcn_s_setprio(0);
    if (tt + 2 < nt)      asm volatile("s_waitcnt vmcnt(6)" ::: "memory");
    else if (tt + 1 < nt) asm volatile("s_waitcnt vmcnt(0)" ::: "memory");
    __builtin_amdgcn_s_barrier();

    { u16* x_ = curA; curA = nxtA; nxtA = x_; }
    { u16* y_ = curB; curB = nxtB; nxtB = y_; }
  }

  // ======================= epilogues =======================
  if (EPI == EPI_QK) {
    // Pure exp+store. Rowsum is computed in the PV kernel (it reads the
    // whole P' row anyway) -> no atomics, no cross-block reduction here.
#pragma unroll
    for (int mi = 0; mi < 8; ++mi) {
#pragma unroll
      for (int i = 0; i < 4; ++i) {
        const int row = m0 + wm * 128 + mi * 16 + lq * 4 + i;
#pragma unroll
        for (int ni = 0; ni < 4; ++ni) {
          const int col = n0 + wn * 64 + ni * 16 + lr;
          const u16 h = f2bf(__expf(acc[mi][ni][i] * 0.03125f));  // unnorm prob
          ((u16*)Cv)[(long)bz * sC + (long)row * ldc + col] = h;
        }
      }
    }
    return;
  }

  if (EPI == EPI_QKV && n0 >= 2048) {
    // ---- V slice: transpose 256x256 tile through LDS in two 128-col halves ----
    u16* tp = lds;                       // [128 cols][264 rows] u16 = 67584 B
    const int e0 = n0 - 2048;
    const long bb = m0 >> 11;            // batch
    const int kbase = m0 & 2047;         // 256-row tile never crosses a batch
    u16* vt_base = auxV + bb * 2097152;
#pragma unroll
    for (int h = 0; h < 2; ++h) {
      __syncthreads();                   // prior LDS use / readback done
      if ((wn >> 1) == h) {
        const int cb = (wn & 1) * 64;    // col within this 128-col half
#pragma unroll
        for (int mi = 0; mi < 8; ++mi) {
          const int row0 = wm * 128 + mi * 16 + lq * 4;
#pragma unroll
          for (int ni = 0; ni < 4; ++ni) {
            const int col = cb + ni * 16 + lr;
            u16x4 v4;
#pragma unroll
            for (int i = 0; i < 4; ++i) v4[i] = f2bf(acc[mi][ni][i]);
            *(u16x4*)(tp + col * 264 + row0) = v4;    // 8B store, 8B-aligned
          }
        }
      }
      __syncthreads();
      // readback: 128 cols x 256 rows = 4096 16B chunks / 512 threads = 8 each
#pragma unroll
      for (int q = 0; q < 8; ++q) {
        const int chunk = q * 512 + t;
        const int c = chunk >> 5, r0 = (chunk & 31) * 8;
        u16x8 v = *(const u16x8*)(tp + c * 264 + r0);
        *(u16x8*)(vt_base + (long)(e0 + h * 128 + c) * 2048 + kbase + r0) = v;  // coalesced
      }
    }
    return;
  }

  // EPI_QKV dense (Q or K slice)
  u16* qkv_out = (n0 < 1024) ? (u16*)Cv : auxK;
  const int nl0 = n0 & 1023;
#pragma unroll
  for (int mi = 0; mi < 8; ++mi) {
#pragma unroll
    for (int i = 0; i < 4; ++i) {
      const int row = m0 + wm * 128 + mi * 16 + lq * 4 + i;
#pragma unroll
      for (int ni = 0; ni < 4; ++ni)
        qkv_out[(long)row * 1024 + nl0 + wn * 64 + ni * 16 + lr] = f2bf(acc[mi][ni][i]);
    }
  }
}

// ---------- legacy 128x128 BT-GEMM (PV) ----------
// EPI_PV now self-computes rowsum: each block reads the FULL P' row
// (K-loop spans all k), so rowsum = sum of its own A-fragments. In-loop
// VALU adds (hidden under MFMA stalls) + 2 shfl_xor over the lq lanes +
// per-row shfl gather in the epilogue. Sum is over the same rounded-bf16
// values the old atomic path summed -> numerically equivalent (f32 order
// differs; old path was nondeterministic atomics anyway).

template <int EPI, int GX, int GY, int GZ>
__global__ __launch_bounds__(256)
void gemm_bt(const u16* __restrict__ A, const u16* __restrict__ B,
             void* __restrict__ Cv, int K, int lda, int ldb, int ldc,
             long sA, long sB, long sC,
             u16* __restrict__ auxK, u16* __restrict__ auxV) {
  __shared__ __align__(16) u16 lds[128 * 128];
  u16* As = lds;
  u16* Bs = lds + 128 * 64;

  const int t = threadIdx.x;
  const int w = t >> 6, l = t & 63;
  int bxs, bys, bz;
  xcd_swz<GX, GY, GZ>(bxs, bys, bz);
  const u16* Ab = A + (long)bz * sA;
  const u16* Bb = B + (long)bz * sB;
  const int m0 = bys * 128, n0 = bxs * 128;
  const int wm = w & 1, wn = w >> 1;
  const int lr = l & 15, lq = l >> 4;
  const int srow = l >> 3;
  const int scol = ((l & 7) ^ ((l >> 3) & 7)) * 8;
  const int rsw = l & 7;

  f32x4 acc[4][4] = {};
  float rsp[4] = {0.f, 0.f, 0.f, 0.f};   // EPI_PV: per-lane partial rowsums

  for (int k0 = 0; k0 < K; k0 += 64) {
    __syncthreads();
#pragma unroll
    for (int c = 0; c < 4; ++c) {
      const int rb = (w * 4 + c) * 8;
      gld_lds16(Ab + (long)(m0 + rb + srow) * lda + k0 + scol, (void*)(As + rb * 64));
      gld_lds16(Bb + (long)(n0 + rb + srow) * ldb + k0 + scol, (void*)(Bs + rb * 64));
    }
    __syncthreads();
#pragma unroll
    for (int j = 0; j < 2; ++j) {
      bf16x8 af[4], bfr[4];
#pragma unroll
      for (int i = 0; i < 4; ++i) {
        const int ch = ((j * 4 + lq) ^ rsw) * 8;
        af[i]  = *(const bf16x8*)(As + (wm * 64 + i * 16 + lr) * 64 + ch);
        bfr[i] = *(const bf16x8*)(Bs + (wn * 64 + i * 16 + lr) * 64 + ch);
      }
      if (EPI == EPI_PV) {
        // af[i] holds 8 k-elems of A-row (wm*64 + i*16 + lr); accumulate.
#pragma unroll
        for (int i = 0; i < 4; ++i)
#pragma unroll
          for (int e = 0; e < 8; ++e)
            rsp[i] += (float)af[i][e];
      }
#pragma unroll
      for (int mi = 0; mi < 4; ++mi)
#pragma unroll
        for (int ni = 0; ni < 4; ++ni)
          acc[mi][ni] = __builtin_amdgcn_mfma_f32_16x16x32_bf16(af[mi], bfr[ni], acc[mi][ni], 0, 0, 0);
    }
  }

  if (EPI == EPI_PV) {
    // reduce over the 4 lq lanes (bits 4-5 of lane id) -> every lane holds
    // the full rowsum of A-row (wm*64 + i*16 + lr)
#pragma unroll
    for (int i = 0; i < 4; ++i) {
      rsp[i] += __shfl_xor(rsp[i], 16, 64);
      rsp[i] += __shfl_xor(rsp[i], 32, 64);
    }
  }

  if (EPI == EPI_QKV && n0 >= 2048) {
    u16* tp = lds;
    __syncthreads();
#pragma unroll
    for (int mi = 0; mi < 4; ++mi) {
      const int row0 = wm * 64 + mi * 16 + lq * 4;
#pragma unroll
      for (int ni = 0; ni < 4; ++ni) {
        const int col = wn * 64 + ni * 16 + lr;
        u16x4 v4;
#pragma unroll
        for (int i = 0; i < 4; ++i) v4[i] = f2bf(acc[mi][ni][i]);
        *(u16x4*)(tp + col * 136 + row0) = v4;
      }
    }
    __syncthreads();
    const int e0 = n0 - 2048;
    const long bb = m0 >> 11;
    const int kbase = m0 & 2047;
    u16* vt_base = auxV + bb * 2097152;
#pragma unroll
    for (int q = 0; q < 8; ++q) {
      const int chunk = q * 256 + t;
      const int c = chunk >> 4, r0 = (chunk & 15) * 8;
      u16x8 v = *(const u16x8*)(tp + c * 136 + r0);
      *(u16x8*)(vt_base + (long)(e0 + c) * 2048 + kbase + r0) = v;
    }
    return;
  }

  u16* qkv_out = nullptr;
  int nl0 = 0;
  if (EPI == EPI_QKV) {
    qkv_out = (n0 < 1024) ? (u16*)Cv : auxK;
    nl0 = n0 & 1023;
  }

#pragma unroll
  for (int mi = 0; mi < 4; ++mi) {
#pragma unroll
    for (int i = 0; i < 4; ++i) {
      const int row = m0 + wm * 64 + mi * 16 + lq * 4 + i;
      float inv;
      if (EPI == EPI_PV) {
        // C-row (mi*16 + lq*4 + i) as A-frag coords: index mi, lr' = lq*4+i.
        // After the lq-reduce any lane with lr == lq*4+i holds it; lanes
        // 0..15 have lr == lane id.
        const float rstot = __shfl(rsp[mi], lq * 4 + i, 64);
        inv = 1.0f / rstot;
      }
#pragma unroll
      for (int ni = 0; ni < 4; ++ni) {
        const float val = acc[mi][ni][i];
        const int col = n0 + wn * 64 + ni * 16 + lr;
        if (EPI == EPI_QKV) {
          qkv_out[(long)row * 1024 + nl0 + wn * 64 + ni * 16 + lr] = f2bf(val);
        } else if (EPI == EPI_QK) {
          const u16 h = f2bf(__expf(val * 0.03125f));
          ((u16*)Cv)[(long)bz * sC + (long)row * ldc + col] = h;
        } else {  // EPI_PV
          ((float*)Cv)[(long)bz * sC + (long)row * ldc + col] = val * inv;
        }
      }
    }
  }
}

// ---------- launch ----------

extern "C" void kernel_launch(void* const* d_in, const int* in_sizes, int n_in,
                              void* d_out, int out_size, void* d_ws, size_t ws_size,
                              hipStream_t stream) {
  (void)in_sizes; (void)n_in; (void)out_size;
  const float* x    = (const float*)d_in[0];
  const float* kern = (const float*)d_in[1];
  float* out = (float*)d_out;
  char* ws = (char*)d_ws;
  const size_t MB = 1024 * 1024;
  u16*   xbf  = (u16*)(ws);              // 16 MB: [8192][1024] bf16
  u16*   WT   = (u16*)(ws + 16 * MB);    //  6 MB: [3][1024][1024] bf16
  u16*   Qc   = (u16*)(ws + 22 * MB);    // 16 MB: [8192][1024] bf16
  u16*   Kc   = (u16*)(ws + 38 * MB);    // 16 MB: [8192][1024] bf16
  u16*   VT   = (u16*)(ws + 54 * MB);    // 16 MB: [4][1024e][2048k] bf16
  u16*   SP   = (u16*)(ws + 70 * MB);    // 32 MB: [4][2048][2048] bf16 unnormalized probs
  if (ws_size < 102 * MB)
    fprintf(stderr, "WARNING: ws_size %zu too small\n", ws_size);

  prep_kernel<<<7168, 256, 0, stream>>>(x, xbf, kern, WT);
  // QKV: M=8192, N=3072 (Q|K|V), K=1024; V transposed in-epilogue into VT
  gemm256_bt<EPI_QKV, 12, 32, 1><<<dim3(12, 32, 1), 512, 0, stream>>>(
      xbf, WT, Qc, 1024, 1024, 1024, 1024, 0, 0, 0, Kc, VT);
  // P'[b][q][k] = exp((Q[b][q,:].K[b][k,:])/32); 256 blocks = 1/CU
  gemm256_bt<EPI_QK, 8, 8, 4><<<dim3(8, 8, 4), 512, 0, stream>>>(
      Qc, Kc, SP, 1024, 1024, 1024, 2048,
      2048L * 1024, 2048L * 1024, 2048L * 2048, nullptr, nullptr);
  // out[b][q][e] = (P'[b][q,:] . VT[b][e,:]) / rowsum(P'[b][q,:])  (self-computed)
  gemm_bt<EPI_PV, 8, 16, 4><<<dim3(8, 16, 4), 256, 0, stream>>>(
      SP, VT, out, 2048, 2048, 2048, 1024,
      2048L * 2048, 1024L * 2048, 2048L * 1024, nullptr, nullptr);
}

// Round 9
// 230.724 us; speedup vs baseline: 1.7151x; 1.0142x over previous
//
#include <hip/hip_runtime.h>
#include <hip/hip_bf16.h>
#include <cstdio>

typedef __bf16  bf16x8 __attribute__((ext_vector_type(8)));
typedef float   f32x4  __attribute__((ext_vector_type(4)));
typedef unsigned short u16;
typedef u16     u16x8  __attribute__((ext_vector_type(8)));
typedef u16     u16x4  __attribute__((ext_vector_type(4)));

// ---------- helpers ----------

__device__ __forceinline__ void gld_lds16(const void* g, void* l) {
  // async global->LDS, 16B per lane; LDS dest is wave-uniform base + lane*16
  __builtin_amdgcn_global_load_lds(
      (const __attribute__((address_space(1))) unsigned int*)g,
      (__attribute__((address_space(3))) unsigned int*)l,
      16, 0, 0);
}

__device__ __forceinline__ u16 f2bf(float f) {
  union { float f; unsigned int u; } c{f};
  unsigned int u = c.u;
  u += 0x7fffu + ((u >> 16) & 1u);   // round-to-nearest-even
  return (u16)(u >> 16);
}

__device__ __forceinline__ float bf2f(u16 h) {
  union { unsigned int u; float f; } c{(unsigned int)h << 16};
  return c.f;
}

enum { EPI_QKV = 0, EPI_QK = 1, EPI_PV = 2 };

// ---------- prep: cast x -> bf16, pack/transpose weights ----------
// grid: [0,4096) cast blocks, [4096,7168) weight tiles

__global__ __launch_bounds__(256) void prep_kernel(const float* __restrict__ x,
                                                   u16* __restrict__ xbf,
                                                   const float* __restrict__ w,
                                                   u16* __restrict__ wt) {
  __shared__ float tile[32][33];
  const int bid = blockIdx.x;
  if (bid < 4096) {
    const int i = (bid * 256 + threadIdx.x) * 8;
    float4 a = *(const float4*)(x + i);
    float4 b = *(const float4*)(x + i + 4);
    u16x8 r;
    r[0] = f2bf(a.x); r[1] = f2bf(a.y); r[2] = f2bf(a.z); r[3] = f2bf(a.w);
    r[4] = f2bf(b.x); r[5] = f2bf(b.y); r[6] = f2bf(b.z); r[7] = f2bf(b.w);
    *(u16x8*)(xbf + i) = r;
  } else {
    // WT[s][e][d] = w[s][d][e], s in 0..2
    const int b2 = bid - 4096;
    const int s = b2 >> 10, r = b2 & 1023;
    const int e0 = (r & 31) * 32, d0 = (r >> 5) * 32;
    const int tx = threadIdx.x & 31, ty = threadIdx.x >> 5;
    const float* in = w + (size_t)s * 1048576;
#pragma unroll
    for (int j = 0; j < 4; ++j)
      tile[ty + j * 8][tx] = in[(size_t)(d0 + ty + j * 8) * 1024 + e0 + tx];
    __syncthreads();
    u16* o = wt + (size_t)s * 1048576;
#pragma unroll
    for (int j = 0; j < 4; ++j)
      o[(size_t)(e0 + ty + j * 8) * 1024 + d0 + tx] = f2bf(tile[tx][ty + j * 8]);
  }
}

// ---------- XCD-aware bijective block swizzle (T1) ----------
// Dispatch order is x-fastest; block d lands on XCD d%8. Remap so each XCD
// owns a CONTIGUOUS run of logical tiles (consecutive x share the A-panel ->
// panel stays in that XCD's L2). Requires NWG % 8 == 0 (all our grids).

template <int GX, int GY, int GZ>
__device__ __forceinline__ void xcd_swz(int& bx, int& by, int& bz) {
  constexpr int NWG = GX * GY * GZ;
  static_assert(NWG % 8 == 0, "grid must be divisible by 8");
  constexpr int Q8 = NWG / 8;
  int flat = blockIdx.x + GX * (blockIdx.y + GY * blockIdx.z);
  flat = (flat & 7) * Q8 + (flat >> 3);
  bx = flat % GX;
  by = (flat / GX) % GY;
  bz = flat / (GX * GY);
}

// ================= 256x256 8-phase BT-GEMM =================
// Used ONLY where its grid is exactly tail-free at 1 block/CU (QK: 256
// blocks). For QKV (384 blocks -> 1.5 rounds at 1/CU) the legacy 128^2
// kernel at 2 blocks/CU is measurably faster (r0: 64.3 vs r8: 72.7 us).
// Stage ledger (verified r2/r4): P1 stages (t+1)A1->nxt.A1; P2 none;
// P3 (t+2)B0->cur.B0; P4 (t+2)B1->cur.B1 + (t+2)A0->cur.A0; vmcnt(6) at P4.

__device__ __forceinline__ void stage_half(const u16* __restrict__ g, int ld, int k0,
                                           u16* ldsb, int w, int l) {
  const int srow = l >> 3;                          // row within 8-row chunk
  const int scol = ((l & 7) ^ (srow & 7)) * 8;      // swizzled 16B chunk (u16 units)
#pragma unroll
  for (int q = 0; q < 2; ++q) {
    const int r = w * 16 + q * 8;                   // 8 waves x 2 x 8 rows = 128
    gld_lds16(g + (long)(r + srow) * ld + k0 + scol, (void*)(ldsb + r * 64));
  }
}

template <int EPI, int GX, int GY, int GZ>
__global__ __launch_bounds__(512, 2)
void gemm256_bt(const u16* __restrict__ A, const u16* __restrict__ B,
                void* __restrict__ Cv, int K, int lda, int ldb, int ldc,
                long sA, long sB, long sC,
                u16* __restrict__ auxK, u16* __restrict__ auxV) {
  __shared__ __align__(16) u16 lds[65536];          // 128 KiB

  const int t = threadIdx.x;
  const int w = t >> 6, l = t & 63;
  const int wm = w >> 2, wn = w & 3;
  const int lr = l & 15, lq = l >> 4;
  const int rsw = l & 7;                            // read-side swizzle key
  int bxs, bys, bz;
  xcd_swz<GX, GY, GZ>(bxs, bys, bz);
  const int m0 = bys * 256, n0 = bxs * 256;
  const u16* Ar = A + (long)bz * sA + (long)m0 * lda;
  const u16* Br = B + (long)bz * sB + (long)n0 * ldb;

  u16* curA = lds;
  u16* curB = lds + 16384;
  u16* nxtA = lds + 32768;
  u16* nxtB = lds + 49152;

  const int nt = K >> 6;

  f32x4 acc[8][4] = {};

  // ---- prologue: tile0 {A0,B0,B1,A1} -> cur; tile1 {A0,B0,B1} -> nxt ----
  stage_half(Ar,             lda, 0, curA,        w, l);
  stage_half(Br,             ldb, 0, curB,        w, l);
  stage_half(Br + 128 * ldb, ldb, 0, curB + 8192, w, l);
  stage_half(Ar + 128 * lda, lda, 0, curA + 8192, w, l);
  asm volatile("s_waitcnt vmcnt(4)" ::: "memory");
  if (nt > 1) {
    stage_half(Ar,             lda, 64, nxtA,        w, l);
    stage_half(Br,             ldb, 64, nxtB,        w, l);
    stage_half(Br + 128 * ldb, ldb, 64, nxtB + 8192, w, l);
    asm volatile("s_waitcnt vmcnt(6)" ::: "memory");   // tile0 fully landed
  } else {
    asm volatile("s_waitcnt vmcnt(0)" ::: "memory");
  }
  __builtin_amdgcn_s_barrier();

  for (int tt = 0; tt < nt; ++tt) {
    const int kc = tt << 6;
    bf16x8 a0[4][2], a1[4][2], b0[2][2], b1[2][2];

    // -------- phase 1: read A-half-lo(8) + B-quarter-0(4); stage (t+1)A1 ----
#pragma unroll
    for (int mi = 0; mi < 4; ++mi)
#pragma unroll
      for (int j = 0; j < 2; ++j)
        a0[mi][j] = *(const bf16x8*)(curA + (wm * 128 + mi * 16 + lr) * 64 +
                                     (((j * 4 + lq) ^ rsw) * 8));
#pragma unroll
    for (int ni = 0; ni < 2; ++ni)
#pragma unroll
      for (int j = 0; j < 2; ++j)
        b0[ni][j] = *(const bf16x8*)(curB + (wn * 64 + ni * 16 + lr) * 64 +
                                     (((j * 4 + lq) ^ rsw) * 8));
    if (tt + 1 < nt)
      stage_half(Ar + 128 * lda, lda, kc + 64, nxtA + 8192, w, l);
    __builtin_amdgcn_s_barrier();
    asm volatile("s_waitcnt lgkmcnt(0)" ::: "memory");
    __builtin_amdgcn_sched_barrier(0);
    __builtin_amdgcn_s_setprio(1);
#pragma unroll
    for (int mi = 0; mi < 4; ++mi)
#pragma unroll
      for (int ni = 0; ni < 2; ++ni)
#pragma unroll
        for (int j = 0; j < 2; ++j)
          acc[mi][ni] = __builtin_amdgcn_mfma_f32_16x16x32_bf16(a0[mi][j], b0[ni][j], acc[mi][ni], 0, 0, 0);
    __builtin_amdgcn_s_setprio(0);
    __builtin_amdgcn_s_barrier();

    // -------- phase 2: read B-quarter-1(4); no stage (cur.A live till P3) ---
#pragma unroll
    for (int ni = 0; ni < 2; ++ni)
#pragma unroll
      for (int j = 0; j < 2; ++j)
        b1[ni][j] = *(const bf16x8*)(curB + (wn * 64 + (ni + 2) * 16 + lr) * 64 +
                                     (((j * 4 + lq) ^ rsw) * 8));
    __builtin_amdgcn_s_barrier();
    asm volatile("s_waitcnt lgkmcnt(0)" ::: "memory");
    __builtin_amdgcn_sched_barrier(0);
    __builtin_amdgcn_s_setprio(1);
#pragma unroll
    for (int mi = 0; mi < 4; ++mi)
#pragma unroll
      for (int ni = 0; ni < 2; ++ni)
#pragma unroll
        for (int j = 0; j < 2; ++j)
          acc[mi][ni + 2] = __builtin_amdgcn_mfma_f32_16x16x32_bf16(a0[mi][j], b1[ni][j], acc[mi][ni + 2], 0, 0, 0);
    __builtin_amdgcn_s_setprio(0);
    __builtin_amdgcn_s_barrier();

    // -------- phase 3: read A-half-hi(8); stage (t+2)B0 ---------------------
#pragma unroll
    for (int mi = 0; mi < 4; ++mi)
#pragma unroll
      for (int j = 0; j < 2; ++j)
        a1[mi][j] = *(const bf16x8*)(curA + (wm * 128 + (mi + 4) * 16 + lr) * 64 +
                                     (((j * 4 + lq) ^ rsw) * 8));
    if (tt + 2 < nt)
      stage_half(Br, ldb, kc + 128, curB, w, l);
    __builtin_amdgcn_s_barrier();
    asm volatile("s_waitcnt lgkmcnt(0)" ::: "memory");
    __builtin_amdgcn_sched_barrier(0);
    __builtin_amdgcn_s_setprio(1);
#pragma unroll
    for (int mi = 0; mi < 4; ++mi)
#pragma unroll
      for (int ni = 0; ni < 2; ++ni)
#pragma unroll
        for (int j = 0; j < 2; ++j)
          acc[mi + 4][ni + 2] = __builtin_amdgcn_mfma_f32_16x16x32_bf16(a1[mi][j], b1[ni][j], acc[mi + 4][ni + 2], 0, 0, 0);
    __builtin_amdgcn_s_setprio(0);
    __builtin_amdgcn_s_barrier();

    // -------- phase 4: stage (t+2)B1 + (t+2)A0; MFMA hi,lo; tile-end vmcnt --
    if (tt + 2 < nt) {
      stage_half(Br + 128 * ldb, ldb, kc + 128, curB + 8192, w, l);
      stage_half(Ar,             lda, kc + 128, curA,        w, l);
    }
    __builtin_amdgcn_s_barrier();
    __builtin_amdgcn_sched_barrier(0);
    __builtin_amdgcn_s_setprio(1);
#pragma unroll
    for (int mi = 0; mi < 4; ++mi)
#pragma unroll
      for (int ni = 0; ni < 2; ++ni)
#pragma unroll
        for (int j = 0; j < 2; ++j)
          acc[mi + 4][ni] = __builtin_amdgcn_mfma_f32_16x16x32_bf16(a1[mi][j], b0[ni][j], acc[mi + 4][ni], 0, 0, 0);
    __builtin_amdgcn_s_setprio(0);
    if (tt + 2 < nt)      asm volatile("s_waitcnt vmcnt(6)" ::: "memory");
    else if (tt + 1 < nt) asm volatile("s_waitcnt vmcnt(0)" ::: "memory");
    __builtin_amdgcn_s_barrier();

    { u16* x_ = curA; curA = nxtA; nxtA = x_; }
    { u16* y_ = curB; curB = nxtB; nxtB = y_; }
  }

  // ======================= epilogues =======================
  if (EPI == EPI_QK) {
    // Pure exp+store. Rowsum is computed in the PV kernel (it reads the
    // whole P' row anyway) -> no atomics, no cross-block reduction here.
#pragma unroll
    for (int mi = 0; mi < 8; ++mi) {
#pragma unroll
      for (int i = 0; i < 4; ++i) {
        const int row = m0 + wm * 128 + mi * 16 + lq * 4 + i;
#pragma unroll
        for (int ni = 0; ni < 4; ++ni) {
          const int col = n0 + wn * 64 + ni * 16 + lr;
          const u16 h = f2bf(__expf(acc[mi][ni][i] * 0.03125f));  // unnorm prob
          ((u16*)Cv)[(long)bz * sC + (long)row * ldc + col] = h;
        }
      }
    }
    return;
  }

  // EPI_QKV dense (unused in current launch config; kept for completeness)
  u16* qkv_out = (n0 < 1024) ? (u16*)Cv : auxK;
  const int nl0 = n0 & 1023;
#pragma unroll
  for (int mi = 0; mi < 8; ++mi) {
#pragma unroll
    for (int i = 0; i < 4; ++i) {
      const int row = m0 + wm * 128 + mi * 16 + lq * 4 + i;
#pragma unroll
      for (int ni = 0; ni < 4; ++ni)
        qkv_out[(long)row * 1024 + nl0 + wn * 64 + ni * 16 + lr] = f2bf(acc[mi][ni][i]);
    }
  }
  (void)auxV;
}

// ---------- legacy 128x128 BT-GEMM (QKV + PV) ----------
// 4 waves, 34 KiB max LDS -> 2 blocks/CU. QKV grid 24x64 = 1536 = 6/CU,
// tail-free (measured 64.3 us in r0 vs 72.7 for the 256^2 variant).
// EPI_QKV: n0<2048 dense Q/K stores; n0>=2048 V-transpose through LDS -> VT.
// EPI_PV: self-computes rowsum from its A-fragments (reads full P' row).

template <int EPI, int GX, int GY, int GZ>
__global__ __launch_bounds__(256)
void gemm_bt(const u16* __restrict__ A, const u16* __restrict__ B,
             void* __restrict__ Cv, int K, int lda, int ldb, int ldc,
             long sA, long sB, long sC,
             u16* __restrict__ auxK, u16* __restrict__ auxV) {
  constexpr int LDS_U16 = (EPI == EPI_QKV) ? (128 * 136) : (128 * 128);
  __shared__ __align__(16) u16 lds[LDS_U16];
  u16* As = lds;
  u16* Bs = lds + 128 * 64;

  const int t = threadIdx.x;
  const int w = t >> 6, l = t & 63;
  int bxs, bys, bz;
  xcd_swz<GX, GY, GZ>(bxs, bys, bz);
  const u16* Ab = A + (long)bz * sA;
  const u16* Bb = B + (long)bz * sB;
  const int m0 = bys * 128, n0 = bxs * 128;
  const int wm = w & 1, wn = w >> 1;
  const int lr = l & 15, lq = l >> 4;
  const int srow = l >> 3;
  const int scol = ((l & 7) ^ ((l >> 3) & 7)) * 8;
  const int rsw = l & 7;

  f32x4 acc[4][4] = {};
  float rsp[4] = {0.f, 0.f, 0.f, 0.f};   // EPI_PV: per-lane partial rowsums

  for (int k0 = 0; k0 < K; k0 += 64) {
    __syncthreads();
#pragma unroll
    for (int c = 0; c < 4; ++c) {
      const int rb = (w * 4 + c) * 8;
      gld_lds16(Ab + (long)(m0 + rb + srow) * lda + k0 + scol, (void*)(As + rb * 64));
      gld_lds16(Bb + (long)(n0 + rb + srow) * ldb + k0 + scol, (void*)(Bs + rb * 64));
    }
    __syncthreads();
#pragma unroll
    for (int j = 0; j < 2; ++j) {
      bf16x8 af[4], bfr[4];
#pragma unroll
      for (int i = 0; i < 4; ++i) {
        const int ch = ((j * 4 + lq) ^ rsw) * 8;
        af[i]  = *(const bf16x8*)(As + (wm * 64 + i * 16 + lr) * 64 + ch);
        bfr[i] = *(const bf16x8*)(Bs + (wn * 64 + i * 16 + lr) * 64 + ch);
      }
      if (EPI == EPI_PV) {
        // af[i] holds 8 k-elems of A-row (wm*64 + i*16 + lr); accumulate.
#pragma unroll
        for (int i = 0; i < 4; ++i)
#pragma unroll
          for (int e = 0; e < 8; ++e)
            rsp[i] += (float)af[i][e];
      }
#pragma unroll
      for (int mi = 0; mi < 4; ++mi)
#pragma unroll
        for (int ni = 0; ni < 4; ++ni)
          acc[mi][ni] = __builtin_amdgcn_mfma_f32_16x16x32_bf16(af[mi], bfr[ni], acc[mi][ni], 0, 0, 0);
    }
  }

  if (EPI == EPI_PV) {
    // reduce over the 4 lq lanes -> every lane holds the full rowsum of
    // A-row (wm*64 + i*16 + lr)
#pragma unroll
    for (int i = 0; i < 4; ++i) {
      rsp[i] += __shfl_xor(rsp[i], 16, 64);
      rsp[i] += __shfl_xor(rsp[i], 32, 64);
    }
  }

  if (EPI == EPI_QKV && n0 >= 2048) {
    // ---- V slice: transpose 128x128 tile through LDS, coalesced 16B stores ----
    u16* tp = lds;  // [128 cols][136 rows-padded] u16 = 34816 B
    __syncthreads();  // all frag reads done; safe to overwrite As/Bs
#pragma unroll
    for (int mi = 0; mi < 4; ++mi) {
      const int row0 = wm * 64 + mi * 16 + lq * 4;
#pragma unroll
      for (int ni = 0; ni < 4; ++ni) {
        const int col = wn * 64 + ni * 16 + lr;
        u16x4 v4;
#pragma unroll
        for (int i = 0; i < 4; ++i) v4[i] = f2bf(acc[mi][ni][i]);
        *(u16x4*)(tp + col * 136 + row0) = v4;   // 8B store, 8B-aligned
      }
    }
    __syncthreads();
    const int e0 = n0 - 2048;
    const long bb = m0 >> 11;           // batch
    const int kbase = m0 & 2047;
    u16* vt_base = auxV + bb * 2097152;
#pragma unroll
    for (int q = 0; q < 8; ++q) {
      const int chunk = q * 256 + t;
      const int c = chunk >> 4, r0 = (chunk & 15) * 8;
      u16x8 v = *(const u16x8*)(tp + c * 136 + r0);      // b128, conflict-free
      *(u16x8*)(vt_base + (long)(e0 + c) * 2048 + kbase + r0) = v;  // coalesced
    }
    return;
  }

  u16* qkv_out = nullptr;
  int nl0 = 0;
  if (EPI == EPI_QKV) {
    qkv_out = (n0 < 1024) ? (u16*)Cv : auxK;
    nl0 = n0 & 1023;
  }

#pragma unroll
  for (int mi = 0; mi < 4; ++mi) {
#pragma unroll
    for (int i = 0; i < 4; ++i) {
      const int row = m0 + wm * 64 + mi * 16 + lq * 4 + i;
      float inv;
      if (EPI == EPI_PV) {
        // C-row (mi*16 + lq*4 + i) as A-frag coords: index mi, lr' = lq*4+i.
        const float rstot = __shfl(rsp[mi], lq * 4 + i, 64);
        inv = 1.0f / rstot;
      }
#pragma unroll
      for (int ni = 0; ni < 4; ++ni) {
        const float val = acc[mi][ni][i];
        const int col = n0 + wn * 64 + ni * 16 + lr;
        if (EPI == EPI_QKV) {
          qkv_out[(long)row * 1024 + nl0 + wn * 64 + ni * 16 + lr] = f2bf(val);
        } else if (EPI == EPI_QK) {
          const u16 h = f2bf(__expf(val * 0.03125f));
          ((u16*)Cv)[(long)bz * sC + (long)row * ldc + col] = h;
        } else {  // EPI_PV
          ((float*)Cv)[(long)bz * sC + (long)row * ldc + col] = val * inv;
        }
      }
    }
  }
}

// ---------- launch ----------

extern "C" void kernel_launch(void* const* d_in, const int* in_sizes, int n_in,
                              void* d_out, int out_size, void* d_ws, size_t ws_size,
                              hipStream_t stream) {
  (void)in_sizes; (void)n_in; (void)out_size;
  const float* x    = (const float*)d_in[0];
  const float* kern = (const float*)d_in[1];
  float* out = (float*)d_out;
  char* ws = (char*)d_ws;
  const size_t MB = 1024 * 1024;
  u16*   xbf  = (u16*)(ws);              // 16 MB: [8192][1024] bf16
  u16*   WT   = (u16*)(ws + 16 * MB);    //  6 MB: [3][1024][1024] bf16
  u16*   Qc   = (u16*)(ws + 22 * MB);    // 16 MB: [8192][1024] bf16
  u16*   Kc   = (u16*)(ws + 38 * MB);    // 16 MB: [8192][1024] bf16
  u16*   VT   = (u16*)(ws + 54 * MB);    // 16 MB: [4][1024e][2048k] bf16
  u16*   SP   = (u16*)(ws + 70 * MB);    // 32 MB: [4][2048][2048] bf16 unnormalized probs
  if (ws_size < 102 * MB)
    fprintf(stderr, "WARNING: ws_size %zu too small\n", ws_size);

  prep_kernel<<<7168, 256, 0, stream>>>(x, xbf, kern, WT);
  // QKV: M=8192, N=3072 (Q|K|V), K=1024; legacy 128^2: 1536 blocks = 6/CU
  // tail-free (measured faster than 256^2's 384-block 1.5-round grid).
  // V slice transposed in-epilogue into VT.
  gemm_bt<EPI_QKV, 24, 64, 1><<<dim3(24, 64, 1), 256, 0, stream>>>(
      xbf, WT, Qc, 1024, 1024, 1024, 1024, 0, 0, 0, Kc, VT);
  // P'[b][q][k] = exp((Q[b][q,:].K[b][k,:])/32); 256^2: 256 blocks = 1/CU
  gemm256_bt<EPI_QK, 8, 8, 4><<<dim3(8, 8, 4), 512, 0, stream>>>(
      Qc, Kc, SP, 1024, 1024, 1024, 2048,
      2048L * 1024, 2048L * 1024, 2048L * 2048, nullptr, nullptr);
  // out[b][q][e] = (P'[b][q,:] . VT[b][e,:]) / rowsum(P'[b][q,:])  (self-computed)
  gemm_bt<EPI_PV, 8, 16, 4><<<dim3(8, 16, 4), 256, 0, stream>>>(
      SP, VT, out, 2048, 2048, 2048, 1024,
      2048L * 2048, 1024L * 2048, 2048L * 1024, nullptr, nullptr);
}